// Round 7
// baseline (219.251 us; speedup 1.0000x reference)
//
#include <hip/hip_runtime.h>
#include <hip/hip_bf16.h>
#include <stdint.h>

// Problem constants
#define D_MODEL 1024
#define BATCH   4
#define SEQ     4096
#define M_TOTAL (BATCH*SEQ)   // 16384
#define KDIM    1024
#define NTOT    2048          // combined N (z cols 0..1023, h cols 1024..2047)

// Scan chunking
#define NC 128
#define CL (SEQ/NC)           // 32

// GEMM tiling: 128x256 tile, BK=32, 8 waves (2M x 4N, wave 64x64), triple-buffer
#define GBM 128
#define GBN 256
#define GBK 32
#define GNT (KDIM/GBK)        // 32 K-steps
#define BUFS 12288            // shorts per LDS buffer (24 KB: A 8KB + B 16KB)

typedef __bf16 bf16x8 __attribute__((ext_vector_type(8)));
typedef float  f32x4  __attribute__((ext_vector_type(4)));
typedef unsigned short u16x4 __attribute__((ext_vector_type(4)));

static __device__ __forceinline__ unsigned short f2bf(float f) {
  unsigned u = __builtin_bit_cast(unsigned, f);
  u += 0x7FFFu + ((u >> 16) & 1u);     // round-to-nearest-even
  return (unsigned short)(u >> 16);
}
static __device__ __forceinline__ float bf2f(unsigned short u) {
  return __builtin_bit_cast(float, (unsigned)u << 16);
}

// ---------------- K0a: x (fp32) -> bf16 ----------------
__global__ __launch_bounds__(256) void k_cvt_x(const float* __restrict__ x,
                                               unsigned short* __restrict__ xb) {
  int i = blockIdx.x * 256 + threadIdx.x;          // 4 elems each
  float4 v = ((const float4*)x)[i];
  ushort4 o;
  o.x = f2bf(v.x); o.y = f2bf(v.y); o.z = f2bf(v.z); o.w = f2bf(v.w);
  ((ushort4*)xb)[i] = o;
}

// ---------------- K0b: W (fp32 [d][e]) -> bf16 transposed [e][d] ----------------
__global__ void k_cvt_wT(const float* __restrict__ Wz, const float* __restrict__ Wh,
                         unsigned short* __restrict__ WzT, unsigned short* __restrict__ WhT) {
  __shared__ float tile[32][33];
  const float* W = blockIdx.z ? Wh : Wz;
  unsigned short* O = blockIdx.z ? WhT : WzT;
  int bx = blockIdx.x * 32;   // e base
  int by = blockIdx.y * 32;   // d base
  int tx = threadIdx.x, ty = threadIdx.y; // 32 x 8
  for (int yy = ty; yy < 32; yy += 8)
    tile[yy][tx] = W[(size_t)(by + yy) * D_MODEL + bx + tx];
  __syncthreads();
  for (int yy = ty; yy < 32; yy += 8)
    O[(size_t)(bx + yy) * D_MODEL + by + tx] = f2bf(tile[tx][yy]);
}

// ---------------- K1: GEMM  [P|Q](bf16) = xb @ Wall^T ---------------------------
// Round-2 pipeline discipline (proven 712 TF: triple-buffer, depth-2 prefetch,
// counted vmcnt, plain barriers) at a 128x256 tile so TWO blocks fit per CU:
//   acc 4x4 (64 VGPR) + 72 KB LDS + __launch_bounds__(512,4) -> 16 waves/CU.
// Cross-block overlap hides the stage/drain phases that capped round 2 at 29%.
// Frag-major LDS [kc][row][8bf16]: conflict-free ds_read_b128, linear
// global_load_lds dest. Swapped MFMA operands -> packed 8B epilogue stores.
__global__ __launch_bounds__(512, 4) void k_gemm2b(
    const unsigned short* __restrict__ xb,    // [M][K] bf16
    const unsigned short* __restrict__ Wall,  // [2048][K] bf16 ([WzT;WhT])
    unsigned short* __restrict__ P, unsigned short* __restrict__ Q)
{
  __shared__ __attribute__((aligned(16))) unsigned short lds[3 * BUFS]; // 72 KB

  const int tid  = threadIdx.x;
  const int wave = tid >> 6;
  const int lane = tid & 63;

  // XCD-bijective swizzle (1024 blocks, 8 XCDs, 128/XCD): XCD x gets
  // bm-chunk [x*16, x*16+16) x all 8 bn -> 8 MB working set per L2.
  const int wgid = (blockIdx.x & 7) * 128 + (blockIdx.x >> 3);
  const int bm = wgid >> 3;
  const int bn = wgid & 7;
  const int m0 = bm * GBM;
  const int n0 = bn * GBN;

  const int wr = wave >> 2;            // 0..1 (64 rows each)
  const int wc = wave & 3;             // 0..3 (64 cols each)
  const int lr = lane & 15;
  const int lc = lane >> 4;            // k-chunk 0..3

  f32x4 acc[4][4];
  #pragma unroll
  for (int i = 0; i < 4; ++i)
    #pragma unroll
    for (int j = 0; j < 4; ++j) acc[i][j] = (f32x4){0.f, 0.f, 0.f, 0.f};

  // staging: 1536 16B-chunks (A 512: [kc4][row128]; B 1024: [kc4][row256]),
  // 3 per thread, wave-uniform kc so LDS dest = base + lane*16B (linear).
  const int aRow = tid & 127, aKc = tid >> 7;                 // A chunk = tid
  const int bRow1 = tid & 255, bKc1 = tid >> 8;               // B chunk = tid
  const int bKc2 = bKc1 + 2;                                  // B chunk = tid+512
  // LDS short-offsets (A at 0, B at 4096)
  const int aDst = aKc * 1024 + aRow * 8;
  const int bDst1 = 4096 + bKc1 * 2048 + bRow1 * 8;
  const int bDst2 = 4096 + bKc2 * 2048 + bRow1 * 8;

  auto stage = [&](int kt, int bufShorts) {
    const int kb = kt * GBK;
    __builtin_amdgcn_global_load_lds(
        (const __attribute__((address_space(1))) unsigned int*)(xb + (size_t)(m0 + aRow) * KDIM + kb + aKc * 8),
        (__attribute__((address_space(3))) unsigned int*)(lds + bufShorts + aDst), 16, 0, 0);
    __builtin_amdgcn_global_load_lds(
        (const __attribute__((address_space(1))) unsigned int*)(Wall + (size_t)(n0 + bRow1) * KDIM + kb + bKc1 * 8),
        (__attribute__((address_space(3))) unsigned int*)(lds + bufShorts + bDst1), 16, 0, 0);
    __builtin_amdgcn_global_load_lds(
        (const __attribute__((address_space(1))) unsigned int*)(Wall + (size_t)(n0 + bRow1) * KDIM + kb + bKc2 * 8),
        (__attribute__((address_space(3))) unsigned int*)(lds + bufShorts + bDst2), 16, 0, 0);
  };

  const int aoff = lc * 1024 + (wr * 64 + lr) * 8;          // + mf*16*8
  const int boff = 4096 + lc * 2048 + (wc * 64 + lr) * 8;   // + nf*16*8

  // prologue: tiles 0,1 in flight; wait tile 0 (its 3 loads) landed
  stage(0, 0);
  stage(1, BUFS);
  asm volatile("s_waitcnt vmcnt(3)" ::: "memory");
  __syncthreads();

  int buf = 0;
  for (int kt = 0; kt < GNT; ++kt) {
    if (kt + 2 < GNT) {
      int db = buf + 2; if (db >= 3) db -= 3;
      stage(kt + 2, db * BUFS);
    }
    const unsigned short* bp = lds + buf * BUFS;

    bf16x8 bfr[4], afr[4];
    #pragma unroll
    for (int nf = 0; nf < 4; ++nf)
      bfr[nf] = *(const bf16x8*)(bp + boff + nf * 128);
    #pragma unroll
    for (int mf = 0; mf < 4; ++mf)
      afr[mf] = *(const bf16x8*)(bp + aoff + mf * 128);

    #pragma unroll
    for (int mf = 0; mf < 4; ++mf)
      #pragma unroll
      for (int nf = 0; nf < 4; ++nf)
        acc[mf][nf] = __builtin_amdgcn_mfma_f32_16x16x32_bf16(bfr[nf], afr[mf], acc[mf][nf], 0, 0, 0);

    // counted wait: newest 3 loads (tile kt+2) may stay in flight
    if (kt + 2 < GNT)      asm volatile("s_waitcnt vmcnt(3)" ::: "memory");
    else if (kt + 1 < GNT) asm volatile("s_waitcnt vmcnt(0)" ::: "memory");
    if (kt + 1 < GNT) __syncthreads();
    buf = (buf == 2) ? 0 : buf + 1;
  }

  // epilogue (swapped-operand D layout, validated rounds 4/6):
  //   row m = m0 + wr*64 + mf*16 + (lane&15)
  //   col n = wc*64 + nf*16 + (lane>>4)*4 + r  -> one 8B store per frag
  unsigned short* Cout = (bn < 4) ? P : Q;
  const int colb = (bn < 4) ? n0 : (n0 - 1024);
  const int jm  = lane & 15;
  const int rn4 = (lane >> 4) * 4;
  #pragma unroll
  for (int mf = 0; mf < 4; ++mf) {
    const size_t row = (size_t)(m0 + wr * 64 + mf * 16 + jm);
    #pragma unroll
    for (int nf = 0; nf < 4; ++nf) {
      const size_t ncol = (size_t)(colb + wc * 64 + nf * 16 + rn4);
      u16x4 pk;
      pk[0] = f2bf(acc[mf][nf][0]);
      pk[1] = f2bf(acc[mf][nf][1]);
      pk[2] = f2bf(acc[mf][nf][2]);
      pk[3] = f2bf(acc[mf][nf][3]);
      *(u16x4*)(Cout + row * D_MODEL + ncol) = pk;
    }
  }
}

// ---------------- K2: per-chunk scan aggregates (bf16 preacts) -----------------
__global__ __launch_bounds__(256) void k_scan_agg(
    const unsigned short* __restrict__ P, const unsigned short* __restrict__ Q,
    const float* __restrict__ bz, const float* __restrict__ bh,
    float* __restrict__ Aagg, float* __restrict__ Bagg)
{
  int c = blockIdx.x & (NC - 1);
  int b = blockIdx.x >> 7;
  int d = threadIdx.x * 4;
  f32x4 vbz = *(const f32x4*)(bz + d);
  f32x4 vbh = *(const f32x4*)(bh + d);
  f32x4 A = {1.f, 1.f, 1.f, 1.f}, Bv = {0.f, 0.f, 0.f, 0.f};
  size_t base = ((size_t)b * SEQ + (size_t)c * CL) * D_MODEL + d;
  for (int t = 0; t < CL; ++t) {
    u16x4 pu = *(const u16x4*)(P + base + (size_t)t * D_MODEL);
    u16x4 qu = *(const u16x4*)(Q + base + (size_t)t * D_MODEL);
    #pragma unroll
    for (int r = 0; r < 4; ++r) {
      float z = 1.f / (1.f + __expf(-(bf2f(pu[r]) + vbz[r])));
      float a = 1.f - z;
      float bb = z * (bf2f(qu[r]) + vbh[r]);
      Bv[r] = a * Bv[r] + bb;
      A[r]  = a * A[r];
    }
  }
  size_t o = ((size_t)b * NC + c) * D_MODEL + d;
  *(f32x4*)(Aagg + o) = A;
  *(f32x4*)(Bagg + o) = Bv;
}

// ---------------- K3: scan across chunk aggregates ----------------
__global__ __launch_bounds__(256) void k_scan_chunks(
    const float* __restrict__ Aagg, const float* __restrict__ Bagg,
    float* __restrict__ Pref)
{
  int idx = blockIdx.x * 256 + threadIdx.x;  // b*1024 + d
  int b = idx >> 10, d = idx & 1023;
  float h = 0.f;
  for (int cc = 0; cc < NC; ++cc) {
    size_t o = ((size_t)b * NC + cc) * D_MODEL + d;
    Pref[o] = h;
    h = Aagg[o] * h + Bagg[o];
  }
}

// ---------------- K4: apply scan, write fp32 h to d_out ----------------
__global__ __launch_bounds__(256) void k_scan_apply(
    const unsigned short* __restrict__ P, const unsigned short* __restrict__ Q,
    const float* __restrict__ bz, const float* __restrict__ bh,
    const float* __restrict__ Pref, float* __restrict__ out)
{
  int c = blockIdx.x & (NC - 1);
  int b = blockIdx.x >> 7;
  int d = threadIdx.x * 4;
  f32x4 vbz = *(const f32x4*)(bz + d);
  f32x4 vbh = *(const f32x4*)(bh + d);
  f32x4 h = *(const f32x4*)(Pref + ((size_t)b * NC + c) * D_MODEL + d);
  size_t base = ((size_t)b * SEQ + (size_t)c * CL) * D_MODEL + d;
  for (int t = 0; t < CL; ++t) {
    u16x4 pu = *(const u16x4*)(P + base + (size_t)t * D_MODEL);
    u16x4 qu = *(const u16x4*)(Q + base + (size_t)t * D_MODEL);
    #pragma unroll
    for (int r = 0; r < 4; ++r) {
      float z = 1.f / (1.f + __expf(-(bf2f(pu[r]) + vbz[r])));
      float a = 1.f - z;
      h[r] = a * h[r] + z * (bf2f(qu[r]) + vbh[r]);
    }
    *(f32x4*)(out + base + (size_t)t * D_MODEL) = h;
  }
}

extern "C" void kernel_launch(void* const* d_in, const int* in_sizes, int n_in,
                              void* d_out, int out_size, void* d_ws, size_t ws_size,
                              hipStream_t stream)
{
  const float* x  = (const float*)d_in[0];
  const float* Wz = (const float*)d_in[1];
  const float* bz = (const float*)d_in[2];
  const float* Wh = (const float*)d_in[3];
  const float* bh = (const float*)d_in[4];

  char* ws = (char*)d_ws;
  unsigned short* xb   = (unsigned short*)(ws);               // 33,554,432
  unsigned short* Wall = (unsigned short*)(ws + 33554432);    //  4,194,304 ([WzT;WhT])
  unsigned short* Pb   = (unsigned short*)(ws + 37748736);    // 33,554,432 (z-preact bf16)
  unsigned short* Qb   = (unsigned short*)(ws + 71303168);    // 33,554,432 (h-preact bf16)
  float* Aagg = (float*)(ws + 104857600);                     //  2,097,152
  float* Bagg = (float*)(ws + 106954752);                     //  2,097,152
  float* Pref = (float*)(ws + 109051904);                     //  2,097,152
  float* out  = (float*)d_out;

  k_cvt_x<<<M_TOTAL * D_MODEL / 4 / 256, 256, 0, stream>>>(x, xb);
  k_cvt_wT<<<dim3(32, 32, 2), dim3(32, 8), 0, stream>>>(Wz, Wh, Wall, Wall + (size_t)1024 * 1024);
  k_gemm2b<<<(M_TOTAL / GBM) * (NTOT / GBN), 512, 0, stream>>>(xb, Wall, Pb, Qb);
  k_scan_agg<<<BATCH * NC, 256, 0, stream>>>(Pb, Qb, bz, bh, Aagg, Bagg);
  k_scan_chunks<<<BATCH * D_MODEL / 256, 256, 0, stream>>>(Aagg, Bagg, Pref);
  k_scan_apply<<<BATCH * NC, 256, 0, stream>>>(Pb, Qb, bz, bh, Pref, out);
}

// Round 8
// 167.444 us; speedup vs baseline: 1.3094x; 1.3094x over previous
//
#include <hip/hip_runtime.h>
#include <hip/hip_bf16.h>
#include <stdint.h>

// Problem constants
#define D_MODEL 1024
#define BATCH   4
#define SEQ     4096
#define M_TOTAL (BATCH*SEQ)   // 16384
#define KDIM    1024
#define NTOT    2048          // combined N (z cols 0..1023, h cols 1024..2047)

// Scan chunking
#define NC 128
#define CL (SEQ/NC)           // 32

// GEMM tiling: round-2 structure (best measured: 96.5us, 712 TF)
#define BM 256
#define BN 256
#define BK 32
#define NT (KDIM/BK)          // 32 K-tiles

typedef __bf16 bf16x8 __attribute__((ext_vector_type(8)));
typedef float  f32x4  __attribute__((ext_vector_type(4)));
typedef unsigned short u16x4 __attribute__((ext_vector_type(4)));

static __device__ __forceinline__ unsigned short f2bf(float f) {
  unsigned u = __builtin_bit_cast(unsigned, f);
  u += 0x7FFFu + ((u >> 16) & 1u);     // round-to-nearest-even
  return (unsigned short)(u >> 16);
}
static __device__ __forceinline__ float bf2f(unsigned short u) {
  return __builtin_bit_cast(float, (unsigned)u << 16);
}

// ---------------- K0a: x (fp32) -> bf16 ----------------
__global__ __launch_bounds__(256) void k_cvt_x(const float* __restrict__ x,
                                               unsigned short* __restrict__ xb) {
  int i = blockIdx.x * 256 + threadIdx.x;          // 4 elems each
  float4 v = ((const float4*)x)[i];
  ushort4 o;
  o.x = f2bf(v.x); o.y = f2bf(v.y); o.z = f2bf(v.z); o.w = f2bf(v.w);
  ((ushort4*)xb)[i] = o;
}

// ---------------- K0b: W (fp32 [d][e]) -> bf16 transposed [e][d] ----------------
__global__ void k_cvt_wT(const float* __restrict__ Wz, const float* __restrict__ Wh,
                         unsigned short* __restrict__ WzT, unsigned short* __restrict__ WhT) {
  __shared__ float tile[32][33];
  const float* W = blockIdx.z ? Wh : Wz;
  unsigned short* O = blockIdx.z ? WhT : WzT;
  int bx = blockIdx.x * 32;   // e base
  int by = blockIdx.y * 32;   // d base
  int tx = threadIdx.x, ty = threadIdx.y; // 32 x 8
  for (int yy = ty; yy < 32; yy += 8)
    tile[yy][tx] = W[(size_t)(by + yy) * D_MODEL + bx + tx];
  __syncthreads();
  for (int yy = ty; yy < 32; yy += 8)
    O[(size_t)(bx + yy) * D_MODEL + by + tx] = f2bf(tile[tx][yy]);
}

// ---------------- K1: GEMM  [P|Q](bf16) = xb @ Wall^T --------------------------
// EXACT round-2 structure (best measured: triple-buffered BK=32, depth-2
// prefetch, counted vmcnt(4), 8 waves of 128x64, frag-major conflict-free LDS)
// with ONE validated delta: swapped MFMA operands -> packed 8B epilogue stores
// (32 x 8B instead of 128 x 2B per thread; validated R4/R6/R7, absmax equal).
__global__ __launch_bounds__(512, 2) void k_gemm8(
    const unsigned short* __restrict__ xb,    // [M][K] bf16
    const unsigned short* __restrict__ Wall,  // [2048][K] bf16 ([WzT;WhT])
    unsigned short* __restrict__ P, unsigned short* __restrict__ Q)
{
  __shared__ __attribute__((aligned(16))) unsigned short lds[3 * 16384]; // 96 KB

  const int tid  = threadIdx.x;
  const int wave = tid >> 6;
  const int lane = tid & 63;
  const int m0 = blockIdx.x * BM;
  const int n0 = blockIdx.y * BN;
  const int wr = wave >> 2;            // 0..1  (128 rows each)
  const int wc = wave & 3;             // 0..3  (64 cols each)
  const int lr = lane & 15;

  // staging pair coords (wave-uniform): pair p -> chunk p>>2, rowblock p&3
  const int p0 = wave * 2, p1 = wave * 2 + 1;
  const int c0 = p0 >> 2, rb0 = p0 & 3;
  const int c1 = p1 >> 2, rb1 = p1 & 3;

  f32x4 acc[8][4];
  #pragma unroll
  for (int i = 0; i < 8; ++i)
    #pragma unroll
    for (int j = 0; j < 4; ++j) acc[i][j] = (f32x4){0.f, 0.f, 0.f, 0.f};

  auto stage = [&](int kt, int bufb) {
    const int kb = kt * BK;
    unsigned short* ldsA = &lds[bufb * 16384];
    unsigned short* ldsB = ldsA + 8192;
    const unsigned short* a0 = xb   + (size_t)(m0 + rb0*64 + lane) * KDIM + kb + c0*8;
    const unsigned short* a1 = xb   + (size_t)(m0 + rb1*64 + lane) * KDIM + kb + c1*8;
    const unsigned short* b0 = Wall + (size_t)(n0 + rb0*64 + lane) * KDIM + kb + c0*8;
    const unsigned short* b1 = Wall + (size_t)(n0 + rb1*64 + lane) * KDIM + kb + c1*8;
    __builtin_amdgcn_global_load_lds((const __attribute__((address_space(1))) unsigned int*)a0,
        (__attribute__((address_space(3))) unsigned int*)(ldsA + (c0*256 + rb0*64)*8), 16, 0, 0);
    __builtin_amdgcn_global_load_lds((const __attribute__((address_space(1))) unsigned int*)a1,
        (__attribute__((address_space(3))) unsigned int*)(ldsA + (c1*256 + rb1*64)*8), 16, 0, 0);
    __builtin_amdgcn_global_load_lds((const __attribute__((address_space(1))) unsigned int*)b0,
        (__attribute__((address_space(3))) unsigned int*)(ldsB + (c0*256 + rb0*64)*8), 16, 0, 0);
    __builtin_amdgcn_global_load_lds((const __attribute__((address_space(1))) unsigned int*)b1,
        (__attribute__((address_space(3))) unsigned int*)(ldsB + (c1*256 + rb1*64)*8), 16, 0, 0);
  };

  // prologue: tiles 0,1 in flight; wait tile 0 landed (tile 1's 4 loads may fly)
  stage(0, 0);
  stage(1, 1);
  asm volatile("s_waitcnt vmcnt(4)" ::: "memory");
  __builtin_amdgcn_s_barrier();

  const int lc  = lane >> 4;
  const int aoff = (lc * 256 + wr * 128 + lr) * 8;   // shorts
  const int boff = (lc * 256 + wc * 64  + lr) * 8;

  int buf = 0;
  for (int kt = 0; kt < NT; ++kt) {
    // prefetch tile kt+2 into the buffer freed at the last barrier
    if (kt + 2 < NT) {
      int db = buf + 2; if (db >= 3) db -= 3;
      stage(kt + 2, db);
    }

    const unsigned short* bufA = &lds[buf * 16384];
    const unsigned short* bufB = bufA + 8192;

    bf16x8 bfrag[4];
    #pragma unroll
    for (int nf = 0; nf < 4; ++nf)
      bfrag[nf] = *(const bf16x8*)(bufB + boff + nf * 128);
    bf16x8 afrag[4];
    #pragma unroll
    for (int mf = 0; mf < 4; ++mf)
      afrag[mf] = *(const bf16x8*)(bufA + aoff + mf * 128);

    __builtin_amdgcn_s_setprio(1);
    #pragma unroll
    for (int mf = 0; mf < 4; ++mf)
      #pragma unroll
      for (int nf = 0; nf < 4; ++nf)
        acc[mf][nf] = __builtin_amdgcn_mfma_f32_16x16x32_bf16(bfrag[nf], afrag[mf], acc[mf][nf], 0, 0, 0);
    __builtin_amdgcn_s_setprio(0);

    #pragma unroll
    for (int mf = 0; mf < 4; ++mf)
      afrag[mf] = *(const bf16x8*)(bufA + aoff + (mf + 4) * 128);

    __builtin_amdgcn_s_setprio(1);
    #pragma unroll
    for (int mf = 0; mf < 4; ++mf)
      #pragma unroll
      for (int nf = 0; nf < 4; ++nf)
        acc[mf + 4][nf] = __builtin_amdgcn_mfma_f32_16x16x32_bf16(bfrag[nf], afrag[mf], acc[mf + 4][nf], 0, 0, 0);
    __builtin_amdgcn_s_setprio(0);

    // counted wait: newest 4 loads (tile kt+2) may stay in flight
    if (kt < NT - 2) asm volatile("s_waitcnt vmcnt(4)" ::: "memory");
    else             asm volatile("s_waitcnt vmcnt(0)" ::: "memory");
    __builtin_amdgcn_s_barrier();
    buf = (buf == 2) ? 0 : buf + 1;
  }

  // epilogue (swapped-operand D layout, validated R4/R6/R7):
  //   row m = m0 + wr*128 + mf*16 + (lane&15)
  //   col n = wc*64 + nf*16 + (lane>>4)*4 + r  -> one 8B store per frag
  unsigned short* Cout = (n0 < 1024) ? P : Q;
  const int colb = (n0 < 1024) ? n0 : (n0 - 1024);
  const int jm  = lane & 15;
  const int rn4 = (lane >> 4) * 4;
  #pragma unroll
  for (int mf = 0; mf < 8; ++mf) {
    const size_t row = (size_t)(m0 + wr * 128 + mf * 16 + jm);
    #pragma unroll
    for (int nf = 0; nf < 4; ++nf) {
      const size_t ncol = (size_t)(colb + wc * 64 + nf * 16 + rn4);
      u16x4 pk;
      pk[0] = f2bf(acc[mf][nf][0]);
      pk[1] = f2bf(acc[mf][nf][1]);
      pk[2] = f2bf(acc[mf][nf][2]);
      pk[3] = f2bf(acc[mf][nf][3]);
      *(u16x4*)(Cout + row * D_MODEL + ncol) = pk;
    }
  }
}

// ---------------- K2: per-chunk scan aggregates (bf16 preacts) -----------------
__global__ __launch_bounds__(256) void k_scan_agg(
    const unsigned short* __restrict__ P, const unsigned short* __restrict__ Q,
    const float* __restrict__ bz, const float* __restrict__ bh,
    float* __restrict__ Aagg, float* __restrict__ Bagg)
{
  int c = blockIdx.x & (NC - 1);
  int b = blockIdx.x >> 7;
  int d = threadIdx.x * 4;
  f32x4 vbz = *(const f32x4*)(bz + d);
  f32x4 vbh = *(const f32x4*)(bh + d);
  f32x4 A = {1.f, 1.f, 1.f, 1.f}, Bv = {0.f, 0.f, 0.f, 0.f};
  size_t base = ((size_t)b * SEQ + (size_t)c * CL) * D_MODEL + d;
  for (int t = 0; t < CL; ++t) {
    u16x4 pu = *(const u16x4*)(P + base + (size_t)t * D_MODEL);
    u16x4 qu = *(const u16x4*)(Q + base + (size_t)t * D_MODEL);
    #pragma unroll
    for (int r = 0; r < 4; ++r) {
      float z = 1.f / (1.f + __expf(-(bf2f(pu[r]) + vbz[r])));
      float a = 1.f - z;
      float bb = z * (bf2f(qu[r]) + vbh[r]);
      Bv[r] = a * Bv[r] + bb;
      A[r]  = a * A[r];
    }
  }
  size_t o = ((size_t)b * NC + c) * D_MODEL + d;
  *(f32x4*)(Aagg + o) = A;
  *(f32x4*)(Bagg + o) = Bv;
}

// ---------------- K3: scan across chunk aggregates ----------------
__global__ __launch_bounds__(256) void k_scan_chunks(
    const float* __restrict__ Aagg, const float* __restrict__ Bagg,
    float* __restrict__ Pref)
{
  int idx = blockIdx.x * 256 + threadIdx.x;  // b*1024 + d
  int b = idx >> 10, d = idx & 1023;
  float h = 0.f;
  for (int cc = 0; cc < NC; ++cc) {
    size_t o = ((size_t)b * NC + cc) * D_MODEL + d;
    Pref[o] = h;
    h = Aagg[o] * h + Bagg[o];
  }
}

// ---------------- K4: apply scan, write fp32 h to d_out ----------------
__global__ __launch_bounds__(256) void k_scan_apply(
    const unsigned short* __restrict__ P, const unsigned short* __restrict__ Q,
    const float* __restrict__ bz, const float* __restrict__ bh,
    const float* __restrict__ Pref, float* __restrict__ out)
{
  int c = blockIdx.x & (NC - 1);
  int b = blockIdx.x >> 7;
  int d = threadIdx.x * 4;
  f32x4 vbz = *(const f32x4*)(bz + d);
  f32x4 vbh = *(const f32x4*)(bh + d);
  f32x4 h = *(const f32x4*)(Pref + ((size_t)b * NC + c) * D_MODEL + d);
  size_t base = ((size_t)b * SEQ + (size_t)c * CL) * D_MODEL + d;
  for (int t = 0; t < CL; ++t) {
    u16x4 pu = *(const u16x4*)(P + base + (size_t)t * D_MODEL);
    u16x4 qu = *(const u16x4*)(Q + base + (size_t)t * D_MODEL);
    #pragma unroll
    for (int r = 0; r < 4; ++r) {
      float z = 1.f / (1.f + __expf(-(bf2f(pu[r]) + vbz[r])));
      float a = 1.f - z;
      h[r] = a * h[r] + z * (bf2f(qu[r]) + vbh[r]);
    }
    *(f32x4*)(out + base + (size_t)t * D_MODEL) = h;
  }
}

extern "C" void kernel_launch(void* const* d_in, const int* in_sizes, int n_in,
                              void* d_out, int out_size, void* d_ws, size_t ws_size,
                              hipStream_t stream)
{
  const float* x  = (const float*)d_in[0];
  const float* Wz = (const float*)d_in[1];
  const float* bz = (const float*)d_in[2];
  const float* Wh = (const float*)d_in[3];
  const float* bh = (const float*)d_in[4];

  char* ws = (char*)d_ws;
  unsigned short* xb   = (unsigned short*)(ws);               // 33,554,432
  unsigned short* Wall = (unsigned short*)(ws + 33554432);    //  4,194,304 ([WzT;WhT])
  unsigned short* Pb   = (unsigned short*)(ws + 37748736);    // 33,554,432 (z-preact bf16)
  unsigned short* Qb   = (unsigned short*)(ws + 71303168);    // 33,554,432 (h-preact bf16)
  float* Aagg = (float*)(ws + 104857600);                     //  2,097,152
  float* Bagg = (float*)(ws + 106954752);                     //  2,097,152
  float* Pref = (float*)(ws + 109051904);                     //  2,097,152
  float* out  = (float*)d_out;

  k_cvt_x<<<M_TOTAL * D_MODEL / 4 / 256, 256, 0, stream>>>(x, xb);
  k_cvt_wT<<<dim3(32, 32, 2), dim3(32, 8), 0, stream>>>(Wz, Wh, Wall, Wall + (size_t)1024 * 1024);
  k_gemm8<<<dim3(M_TOTAL / BM, NTOT / BN), 512, 0, stream>>>(xb, Wall, Pb, Qb);
  k_scan_agg<<<BATCH * NC, 256, 0, stream>>>(Pb, Qb, bz, bh, Aagg, Bagg);
  k_scan_chunks<<<BATCH * D_MODEL / 256, 256, 0, stream>>>(Aagg, Bagg, Pref);
  k_scan_apply<<<BATCH * NC, 256, 0, stream>>>(Pb, Qb, bz, bh, Pref, out);
}